// Round 1
// baseline (299.660 us; speedup 1.0000x reference)
//
#include <hip/hip_runtime.h>
#include <hip/hip_fp16.h>
#include <stdint.h>

#define NN 4096      // nodes
#define FF 512       // in features
#define DD 64        // head dim
#define HH 4         // heads
#define MM 2         // metapaths
#define LOG2E 1.44269504088896340736f
#define ALPHA_LR 0.2f

typedef float f32x4 __attribute__((ext_vector_type(4)));
typedef _Float16 f16x8 __attribute__((ext_vector_type(8)));
typedef _Float16 f16x2 __attribute__((ext_vector_type(2)));
typedef unsigned short u16x2 __attribute__((ext_vector_type(2)));

extern "C" __device__ _Float16 __ocml_exp2_f16(_Float16);

union H4 { ushort4 u; _Float16 h[4]; };
union W8 { f16x8 v; uint32_t w[4]; f16x2 p[4]; };

__device__ inline float fast_exp2(float x) { return __builtin_amdgcn_exp2f(x); }
__device__ inline float fast_rcp(float x) { return __builtin_amdgcn_rcpf(x); }
__device__ inline f32x4 mfma16(f16x8 a, f16x8 b, f32x4 c) {
    return __builtin_amdgcn_mfma_f32_16x16x32_f16(a, b, c, 0, 0, 0);
}
// order-preserving float->uint encode for atomicMax
__device__ inline uint32_t enc_f32(float f) {
    uint32_t u = __float_as_uint(f);
    return (u & 0x80000000u) ? ~u : (u | 0x80000000u);
}
__device__ inline float dec_f32(uint32_t k) {
    uint32_t u = (k & 0x80000000u) ? (k ^ 0x80000000u) : ~k;
    return __uint_as_float(u);
}
// packed f16 {0,1} mask for j-pair k from smeared bits V = rs8 | (rs8<<15)
__device__ inline f16x2 msk01(uint32_t V, int k) {
    uint32_t w = (V >> (2 * k)) & 0x00010001u;
    u16x2 m = __builtin_bit_cast(u16x2, w) * (u16x2){0x3C00, 0x3C00}; // v_pk_mul_lo_u16
    return __builtin_bit_cast(f16x2, m);
}
__device__ inline f16x2 pkmax(f16x2 a, f16x2 b) {
#if __has_builtin(__builtin_elementwise_max)
    return __builtin_elementwise_max(a, b);
#else
    return (f16x2){a[0] > b[0] ? a[0] : b[0], a[1] > b[1] ? a[1] : b[1]};
#endif
}

// ---- fused prep ----
// [0,1024): adj -> transposed bitmask, column-strip blocks with LDS-staged
//           coalesced flush (kills the 8B-scattered lane-0 stores).
//           block = (m, jw, i-oct of 512 rows). reads 256B/wave coalesced,
//           unroll-16 keeps 16 loads in flight per wave (load->ballot dep).
// [1024,1536): W -> wtT f16 (+ m4a init)
__global__ __launch_bounds__(256) void k_prep(const int* __restrict__ adj,
                                              const float* __restrict__ W,
                                              _Float16* __restrict__ wt,
                                              unsigned long long* __restrict__ bitsT,
                                              uint32_t* __restrict__ m4a) {
    const int bid = blockIdx.x;
    if (bid < 1024) {
        __shared__ unsigned long long sw[512];
        const int iq = bid & 7;            // i-oct (512 rows)
        const int jw = (bid >> 3) & 63;    // word column
        const int m  = bid >> 9;           // metapath
        const int w  = threadIdx.x >> 6;
        const int l  = threadIdx.x & 63;
        const int i0 = iq << 9;
        const int* rp = adj + ((size_t)m << 24) + ((size_t)(i0 + (w << 7)) << 12)
                        + (jw << 6) + l;
        for (int t0 = 0; t0 < 128; t0 += 16) {
            int v[16];
            #pragma unroll
            for (int u = 0; u < 16; ++u) v[u] = rp[(size_t)(t0 + u) << 12];
            #pragma unroll
            for (int u = 0; u < 16; ++u) {
                unsigned long long msk = __ballot(v[u] != 0);
                if (l == 0) sw[(w << 7) + t0 + u] = msk;
            }
        }
        __syncthreads();
        {   // coalesced flush: 512 words = 4KB, 16B per thread
            const int k = threadIdx.x;
            unsigned long long* dst = bitsT + (((size_t)m * 64 + jw) << 12) + i0 + 2 * k;
            ulonglong2 val;
            val.x = sw[2 * k];
            val.y = sw[2 * k + 1];
            *(ulonglong2*)dst = val;
        }
    } else {
        int t = (bid - 1024) * 256 + threadIdx.x;  // H*F*D = 131072
        if (t < HH) m4a[t] = 0u;                   // encoded floor
        int c = t >> 9, f = t & 511;
        int h = c >> 6, d = c & 63;
        wt[t] = (_Float16)W[(h * FF + f) * DD + d];
    }
}

// ---- Wh = x @ W[h] -> whT[h*64+d][n] f16 ; fused s1L/s2h/m4a from accumulators ----
// reads x f32 directly (f32->f16 cast fused into A-fragment load; xh round-trip gone)
__global__ __launch_bounds__(512) void k_wh(const float* __restrict__ x,
                                            const _Float16* __restrict__ wt,
                                            const float* __restrict__ a1,
                                            const float* __restrict__ a2,
                                            _Float16* __restrict__ whT,
                                            float* __restrict__ s1L,
                                            _Float16* __restrict__ s2h,
                                            uint32_t* __restrict__ m4a) {
    __shared__ float sred[8][2][16];
    const int wave = threadIdx.x >> 6;
    const int h    = wave & 3;
    const int th   = wave >> 2;
    const int lane = threadIdx.x & 63;
    const int iL   = lane & 15;
    const int quad = lane >> 4;
    const int i0   = blockIdx.x * 16;

    f32x4 acc[2];
    acc[0] = (f32x4){0.f, 0.f, 0.f, 0.f};
    acc[1] = (f32x4){0.f, 0.f, 0.f, 0.f};

    const float* arow = x + (size_t)(i0 + iL) * FF + quad * 8;
    const _Float16* bbase = wt + (size_t)(h * 64 + th * 32 + iL) * FF + quad * 8;

    for (int kc = 0; kc < FF; kc += 32) {
        f32x4 xa = *(const f32x4*)(arow + kc);
        f32x4 xb = *(const f32x4*)(arow + kc + 4);
        f16x8 a;
        #pragma unroll
        for (int r = 0; r < 4; ++r) {
            a[r]     = (_Float16)xa[r];
            a[4 + r] = (_Float16)xb[r];
        }
        #pragma unroll
        for (int u = 0; u < 2; ++u) {
            f16x8 b = *(const f16x8*)(bbase + (size_t)(16 * u) * FF + kc);
            acc[u] = mfma16(a, b, acc[u]);
        }
    }
    #pragma unroll
    for (int u = 0; u < 2; ++u) {
        H4 o;
        #pragma unroll
        for (int r = 0; r < 4; ++r) o.h[r] = (_Float16)acc[u][r];
        *(ushort4*)(whT + (size_t)(h * 64 + th * 32 + 16 * u + iL) * NN + i0 + quad * 4) = o.u;
    }

    // ---- fused s1/s2: dot over this wave's 32 d's, butterfly over iL, LDS over th ----
    const float a1v0 = a1[h * 64 + th * 32 + iL];
    const float a1v1 = a1[h * 64 + th * 32 + 16 + iL];
    const float a2v0 = a2[h * 64 + th * 32 + iL];
    const float a2v1 = a2[h * 64 + th * 32 + 16 + iL];
    #pragma unroll
    for (int r = 0; r < 4; ++r) {
        float p1 = acc[0][r] * a1v0 + acc[1][r] * a1v1;
        float p2 = acc[0][r] * a2v0 + acc[1][r] * a2v1;
        #pragma unroll
        for (int off = 1; off < 16; off <<= 1) {
            p1 += __shfl_xor(p1, off);
            p2 += __shfl_xor(p2, off);
        }
        if (iL == 0) {
            sred[wave][0][quad * 4 + r] = p1;
            sred[wave][1][quad * 4 + r] = p2;
        }
    }
    __syncthreads();
    if (threadIdx.x < 64) {
        int h2  = threadIdx.x >> 4;
        int idx = threadIdx.x & 15;
        float s1 = sred[h2][0][idx] + sred[h2 + 4][0][idx];
        float s2 = sred[h2][1][idx] + sred[h2 + 4][1][idx];
        float s2l = s2 * LOG2E;
        s1L[h2 * NN + i0 + idx] = s1 * LOG2E;
        s2h[h2 * NN + i0 + idx] = (_Float16)s2l;
        float mx = s2l;
        #pragma unroll
        for (int off = 1; off < 16; off <<= 1) mx = fmaxf(mx, __shfl_xor(mx, off));
        if (idx == 0) atomicMax(m4a + h2, enc_f32(mx));
    }
}

// ---- fused masked-attention + elu + metapath sum ----
// grid 256 = (i-group of 64 rows) x head; 512 thr = 8 waves = 8 j-slices of 512.
// bm bitmask loads double-buffered (named bufs, static indexing) so the L2
// latency of each it's 8x8B loads hides under the previous it's MFMA+VALU.
__global__ __launch_bounds__(512, 2) void k_attn(const _Float16* __restrict__ whT,
                                                 const float* __restrict__ s1L,
                                                 const _Float16* __restrict__ s2h,
                                                 const uint32_t* __restrict__ m4a,
                                                 const unsigned long long* __restrict__ bitsT,
                                                 float* __restrict__ out) {
    __shared__ __align__(16) float xr[8][MM][4][16][16]; // [slot][m][t][col][row]
    __shared__ __align__(16) float dr[8][MM][16];

    const int tid  = threadIdx.x;
    const int wave = tid >> 6;
    const int lane = tid & 63;
    const int iL   = lane & 15;
    const int quad = lane >> 4;
    const int h    = blockIdx.x & 3;
    const int i0   = (blockIdx.x >> 2) * 64;      // 64 i-rows per block

    const float m4 = dec_f32(m4a[h]);
    f16x2 A2[4], B2[4];
    #pragma unroll
    for (int s = 0; s < 4; ++s) {
        float s1i = s1L[h * NN + i0 + 16 * s + iL];
        float vv  = s1i + m4;
        float cii = fmaxf(vv, ALPHA_LR * vv);     // lrelu row shift (log2 domain)
        _Float16 a = (_Float16)(s1i - cii);
        _Float16 b = (_Float16)(ALPHA_LR * s1i - cii);
        A2[s] = (f16x2){a, a};
        B2[s] = (f16x2){b, b};
    }
    const f16x2 al2 = (f16x2){(_Float16)ALPHA_LR, (_Float16)ALPHA_LR};

    f32x4 acc[4][MM][4];
    f32x4 accD[4][MM];
    #pragma unroll
    for (int s = 0; s < 4; ++s)
        #pragma unroll
        for (int m = 0; m < MM; ++m) {
            accD[s][m] = (f32x4){0.f, 0.f, 0.f, 0.f};
            #pragma unroll
            for (int t = 0; t < 4; ++t) acc[s][m][t] = (f32x4){0.f, 0.f, 0.f, 0.f};
        }

    f16x8 bones;
    #pragma unroll
    for (int e = 0; e < 8; ++e) bones[e] = (_Float16)1.0f;

    const _Float16* s2row = s2h + h * NN;
    const _Float16* brow = whT + (size_t)(h * 64 + iL) * NN;   // + 16t*NN + j
    const int qshift = quad * 8;
    const int jbase = wave * 512;

    const unsigned long long* pB[MM][4];
    #pragma unroll
    for (int m = 0; m < MM; ++m)
        #pragma unroll
        for (int s = 0; s < 4; ++s)
            pB[m][s] = bitsT + (size_t)m * 64 * NN + i0 + 16 * s + iL;

    auto loadB = [&](unsigned long long (&bm)[MM][4], int it) {
        const int jw = (jbase + it * 64) >> 6;
        #pragma unroll
        for (int m = 0; m < MM; ++m)
            #pragma unroll
            for (int s = 0; s < 4; ++s)
                bm[m][s] = pB[m][s][(size_t)jw * NN];
    };

    auto proc = [&](const unsigned long long (&bm)[MM][4], int it) {
        const int jc = jbase + it * 64;
        #pragma unroll
        for (int half = 0; half < 2; ++half) {
            const int jb = jc + 32 * half;
            // shared b-fragments (amortized over 4 subtiles)
            f16x8 bfr[4];
            #pragma unroll
            for (int t = 0; t < 4; ++t)
                bfr[t] = *(const f16x8*)(brow + (size_t)(16 * t) * NN + jb + qshift);

            const W8 s2v = *(const W8*)(s2row + jb + qshift);  // 8 f16 (4 pairs)
            const int shft = 32 * half + qshift;

            #pragma unroll
            for (int s = 0; s < 4; ++s) {
                uint32_t rs0 = (uint32_t)(bm[0][s] >> shft) & 0xFFu;
                uint32_t rs1 = (uint32_t)(bm[1][s] >> shft) & 0xFFu;
                uint32_t V0 = rs0 | (rs0 << 15);   // bit 2k+1 -> bit 2k+16
                uint32_t V1 = rs1 | (rs1 << 15);
                W8 a0, a1v;
                #pragma unroll
                for (int k = 0; k < 4; ++k) {
                    f16x2 z = s2v.p[k] + A2[s];               // v_pk_add_f16
                    f16x2 l = al2 * s2v.p[k] + B2[s];         // v_pk_fma_f16
                    f16x2 mx = pkmax(z, l);                   // v_pk_max_f16
                    f16x2 p = (f16x2){__ocml_exp2_f16(mx[0]), __ocml_exp2_f16(mx[1])};
                    a0.p[k]  = p * msk01(V0, k);              // v_pk_mul_f16
                    a1v.p[k] = p * msk01(V1, k);
                }
                #pragma unroll
                for (int t = 0; t < 4; ++t) {
                    acc[s][0][t] = mfma16(a0.v, bfr[t], acc[s][0][t]);
                    acc[s][1][t] = mfma16(a1v.v, bfr[t], acc[s][1][t]);
                }
                accD[s][0] = mfma16(a0.v, bones, accD[s][0]);
                accD[s][1] = mfma16(a1v.v, bones, accD[s][1]);
            }
        }
    };

    unsigned long long bmA[MM][4], bmB[MM][4];
    loadB(bmA, 0);
    #pragma unroll 1
    for (int it = 0; it < 8; it += 2) {
        loadB(bmB, it + 1);                // in flight under proc(bmA)
        proc(bmA, it);
        if (it + 2 < 8) loadB(bmA, it + 2); // in flight under proc(bmB)
        proc(bmB, it + 1);
    }

    // ---- epilogue: per s, single 8-slot store + 4-wave finalize (2 syncs/s) ----
    for (int s = 0; s < 4; ++s) {
        __syncthreads();          // previous round's reads complete
        #pragma unroll
        for (int m = 0; m < MM; ++m) {
            #pragma unroll
            for (int t = 0; t < 4; ++t)
                *(f32x4*)&xr[wave][m][t][iL][quad * 4] = acc[s][m][t];
            if (iL == 0) *(f32x4*)&dr[wave][m][quad * 4] = accD[s][m];
        }
        __syncthreads();
        if (wave < 4) {
            const int t = wave;
            f32x4 n0 = (f32x4){0.f, 0.f, 0.f, 0.f};
            f32x4 n1 = (f32x4){0.f, 0.f, 0.f, 0.f};
            f32x4 d0 = (f32x4){0.f, 0.f, 0.f, 0.f};
            f32x4 d1 = (f32x4){0.f, 0.f, 0.f, 0.f};
            #pragma unroll
            for (int sl = 0; sl < 8; ++sl) {
                n0 += *(const f32x4*)&xr[sl][0][t][iL][quad * 4];
                n1 += *(const f32x4*)&xr[sl][1][t][iL][quad * 4];
                d0 += *(const f32x4*)&dr[sl][0][quad * 4];
                d1 += *(const f32x4*)&dr[sl][1][quad * 4];
            }
            const int i0s = i0 + 16 * s;
            #pragma unroll
            for (int r = 0; r < 4; ++r) {
                float v0 = n0[r] * fast_rcp(d0[r]);
                float v1 = n1[r] * fast_rcp(d1[r]);
                float e0 = v0 > 0.f ? v0 : (fast_exp2(v0 * LOG2E) - 1.f);
                float e1 = v1 > 0.f ? v1 : (fast_exp2(v1 * LOG2E) - 1.f);
                out[(size_t)(i0s + quad * 4 + r) * (HH * DD) + h * 64 + 16 * t + iL] = e0 + e1;
            }
        }
    }
}

extern "C" void kernel_launch(void* const* d_in, const int* in_sizes, int n_in,
                              void* d_out, int out_size, void* d_ws, size_t ws_size,
                              hipStream_t stream) {
    const float* x   = (const float*)d_in[0];
    const int*   adj = (const int*)d_in[1];
    const float* W   = (const float*)d_in[2];
    const float* a1  = (const float*)d_in[3];
    const float* a2  = (const float*)d_in[4];
    // d_in[5..7] (Ws, bs, q_sem) mathematically dead: softmax over size-1 axis == 1
    float* out = (float*)d_out;

    char* ws = (char*)d_ws;
    _Float16* wt   = (_Float16*)(ws);                 // 256 KB
    _Float16* whT  = (_Float16*)(ws + 262144);        // 2 MB
    float*    s1L  = (float*)(ws + 2359296);          // 64 KB
    _Float16* s2h  = (_Float16*)(ws + 2424832);       // 32 KB
    uint32_t* m4a  = (uint32_t*)(ws + 2457600);       // 16 B
    unsigned long long* bitsT = (unsigned long long*)(ws + 2490368); // 4 MB

    hipLaunchKernelGGL(k_prep, dim3(1536), dim3(256), 0, stream,
                       adj, W, wt, bitsT, m4a);
    hipLaunchKernelGGL(k_wh, dim3(256), dim3(512), 0, stream,
                       x, wt, a1, a2, whT, s1L, s2h, m4a);
    hipLaunchKernelGGL(k_attn, dim3(256), dim3(512), 0, stream,
                       whT, s1L, s2h, m4a, bitsT, out);
}

// Round 2
// 272.031 us; speedup vs baseline: 1.1016x; 1.1016x over previous
//
#include <hip/hip_runtime.h>
#include <hip/hip_fp16.h>
#include <stdint.h>

#define NN 4096      // nodes
#define FF 512       // in features
#define DD 64        // head dim
#define HH 4         // heads
#define MM 2         // metapaths
#define LOG2E 1.44269504088896340736f
#define ALPHA_LR 0.2f

typedef float f32x4 __attribute__((ext_vector_type(4)));
typedef _Float16 f16x8 __attribute__((ext_vector_type(8)));
typedef _Float16 f16x2 __attribute__((ext_vector_type(2)));
typedef unsigned short u16x2 __attribute__((ext_vector_type(2)));

extern "C" __device__ _Float16 __ocml_exp2_f16(_Float16);

union H4 { ushort4 u; _Float16 h[4]; };
union W8 { f16x8 v; uint32_t w[4]; f16x2 p[4]; };

__device__ inline float fast_exp2(float x) { return __builtin_amdgcn_exp2f(x); }
__device__ inline float fast_rcp(float x) { return __builtin_amdgcn_rcpf(x); }
__device__ inline f32x4 mfma16(f16x8 a, f16x8 b, f32x4 c) {
    return __builtin_amdgcn_mfma_f32_16x16x32_f16(a, b, c, 0, 0, 0);
}
// order-preserving float->uint encode for atomicMax
__device__ inline uint32_t enc_f32(float f) {
    uint32_t u = __float_as_uint(f);
    return (u & 0x80000000u) ? ~u : (u | 0x80000000u);
}
__device__ inline float dec_f32(uint32_t k) {
    uint32_t u = (k & 0x80000000u) ? (k ^ 0x80000000u) : ~k;
    return __uint_as_float(u);
}
// packed f16 {0,1} mask for j-pair k from smeared bits V = rs8 | (rs8<<15)
__device__ inline f16x2 msk01(uint32_t V, int k) {
    uint32_t w = (V >> (2 * k)) & 0x00010001u;
    u16x2 m = __builtin_bit_cast(u16x2, w) * (u16x2){0x3C00, 0x3C00}; // v_pk_mul_lo_u16
    return __builtin_bit_cast(f16x2, m);
}
__device__ inline f16x2 pkmax(f16x2 a, f16x2 b) {
#if __has_builtin(__builtin_elementwise_max)
    return __builtin_elementwise_max(a, b);
#else
    return (f16x2){a[0] > b[0] ? a[0] : b[0], a[1] > b[1] ? a[1] : b[1]};
#endif
}

// ---- fused prep ----
// [0,2048): adj -> transposed bitmask. Sequential grid-stride reads (full
//           channel spread; this is the measured-good pattern) + ballot +
//           lane-0 8B store. Column-strip variant regressed (16KB-stride
//           reads collapsed DRAM BW) — do not reintroduce.
// [2048,2560): W -> wtT f16 (+ m4a init)
__global__ __launch_bounds__(256) void k_prep(const int* __restrict__ adj,
                                              const float* __restrict__ W,
                                              _Float16* __restrict__ wt,
                                              unsigned long long* __restrict__ bitsT,
                                              uint32_t* __restrict__ m4a) {
    const int bid = blockIdx.x;
    if (bid < 2048) {
        // adj int32 {0,1} -> TRANSPOSED bitmask bitsT[m][jw][i] (ull units)
        const long long total = (long long)MM * NN * NN;      // 33554432
        const long long stride = 2048LL * 256;
        long long tid = (long long)bid * 256 + threadIdx.x;
        for (long long e = tid; e < total; e += stride) {
            unsigned long long msk = __ballot(adj[e] != 0);
            if ((threadIdx.x & 63) == 0) {
                long long q = e >> 6;
                int m  = (int)(q >> 18);
                int rem = (int)(q & 262143);
                int i  = rem >> 6;
                int jw = rem & 63;
                bitsT[((size_t)m * 64 + jw) * NN + i] = msk;
            }
        }
    } else {
        int t = (bid - 2048) * 256 + threadIdx.x;  // H*F*D = 131072
        if (t < HH) m4a[t] = 0u;                   // encoded floor
        int c = t >> 9, f = t & 511;
        int h = c >> 6, d = c & 63;
        wt[t] = (_Float16)W[(h * FF + f) * DD + d];
    }
}

// ---- Wh = x @ W[h] -> whT[h*64+d][n] f16 ; fused s1L/s2h/m4a from accumulators ----
// reads x f32 directly (f32->f16 cast fused into A-fragment load; xh round-trip gone)
__global__ __launch_bounds__(512) void k_wh(const float* __restrict__ x,
                                            const _Float16* __restrict__ wt,
                                            const float* __restrict__ a1,
                                            const float* __restrict__ a2,
                                            _Float16* __restrict__ whT,
                                            float* __restrict__ s1L,
                                            _Float16* __restrict__ s2h,
                                            uint32_t* __restrict__ m4a) {
    __shared__ float sred[8][2][16];
    const int wave = threadIdx.x >> 6;
    const int h    = wave & 3;
    const int th   = wave >> 2;
    const int lane = threadIdx.x & 63;
    const int iL   = lane & 15;
    const int quad = lane >> 4;
    const int i0   = blockIdx.x * 16;

    f32x4 acc[2];
    acc[0] = (f32x4){0.f, 0.f, 0.f, 0.f};
    acc[1] = (f32x4){0.f, 0.f, 0.f, 0.f};

    const float* arow = x + (size_t)(i0 + iL) * FF + quad * 8;
    const _Float16* bbase = wt + (size_t)(h * 64 + th * 32 + iL) * FF + quad * 8;

    for (int kc = 0; kc < FF; kc += 32) {
        f32x4 xa = *(const f32x4*)(arow + kc);
        f32x4 xb = *(const f32x4*)(arow + kc + 4);
        f16x8 a;
        #pragma unroll
        for (int r = 0; r < 4; ++r) {
            a[r]     = (_Float16)xa[r];
            a[4 + r] = (_Float16)xb[r];
        }
        #pragma unroll
        for (int u = 0; u < 2; ++u) {
            f16x8 b = *(const f16x8*)(bbase + (size_t)(16 * u) * FF + kc);
            acc[u] = mfma16(a, b, acc[u]);
        }
    }
    #pragma unroll
    for (int u = 0; u < 2; ++u) {
        H4 o;
        #pragma unroll
        for (int r = 0; r < 4; ++r) o.h[r] = (_Float16)acc[u][r];
        *(ushort4*)(whT + (size_t)(h * 64 + th * 32 + 16 * u + iL) * NN + i0 + quad * 4) = o.u;
    }

    // ---- fused s1/s2: dot over this wave's 32 d's, butterfly over iL, LDS over th ----
    const float a1v0 = a1[h * 64 + th * 32 + iL];
    const float a1v1 = a1[h * 64 + th * 32 + 16 + iL];
    const float a2v0 = a2[h * 64 + th * 32 + iL];
    const float a2v1 = a2[h * 64 + th * 32 + 16 + iL];
    #pragma unroll
    for (int r = 0; r < 4; ++r) {
        float p1 = acc[0][r] * a1v0 + acc[1][r] * a1v1;
        float p2 = acc[0][r] * a2v0 + acc[1][r] * a2v1;
        #pragma unroll
        for (int off = 1; off < 16; off <<= 1) {
            p1 += __shfl_xor(p1, off);
            p2 += __shfl_xor(p2, off);
        }
        if (iL == 0) {
            sred[wave][0][quad * 4 + r] = p1;
            sred[wave][1][quad * 4 + r] = p2;
        }
    }
    __syncthreads();
    if (threadIdx.x < 64) {
        int h2  = threadIdx.x >> 4;
        int idx = threadIdx.x & 15;
        float s1 = sred[h2][0][idx] + sred[h2 + 4][0][idx];
        float s2 = sred[h2][1][idx] + sred[h2 + 4][1][idx];
        float s2l = s2 * LOG2E;
        s1L[h2 * NN + i0 + idx] = s1 * LOG2E;
        s2h[h2 * NN + i0 + idx] = (_Float16)s2l;
        float mx = s2l;
        #pragma unroll
        for (int off = 1; off < 16; off <<= 1) mx = fmaxf(mx, __shfl_xor(mx, off));
        if (idx == 0) atomicMax(m4a + h2, enc_f32(mx));
    }
}

// ---- fused masked-attention + elu + metapath sum ----
// grid 256 = (i-group of 64 rows) x head; 512 thr = 8 waves = 8 j-slices of 512.
// __launch_bounds__(512,1): the (512,2) variant capped VGPRs at 128 (CUDA
// min-blocks semantics: 2 blocks/CU -> 4 waves/SIMD), which is exactly the
// size of acc[][][] -> the allocator spilled 512B/thread of accumulator to
// scratch (121MB of HBM writes measured vs 4MB of output). 256-VGPR budget
// keeps everything in registers; epilogue s-loop unrolled so acc is always
// statically indexed (runtime-indexed ext_vector arrays go to scratch).
__global__ __launch_bounds__(512, 1) void k_attn(const _Float16* __restrict__ whT,
                                                 const float* __restrict__ s1L,
                                                 const _Float16* __restrict__ s2h,
                                                 const uint32_t* __restrict__ m4a,
                                                 const unsigned long long* __restrict__ bitsT,
                                                 float* __restrict__ out) {
    __shared__ __align__(16) float xr[8][MM][4][16][16]; // [slot][m][t][col][row]
    __shared__ __align__(16) float dr[8][MM][16];

    const int tid  = threadIdx.x;
    const int wave = tid >> 6;
    const int lane = tid & 63;
    const int iL   = lane & 15;
    const int quad = lane >> 4;
    const int h    = blockIdx.x & 3;
    const int i0   = (blockIdx.x >> 2) * 64;      // 64 i-rows per block

    const float m4 = dec_f32(m4a[h]);
    f16x2 A2[4], B2[4];
    #pragma unroll
    for (int s = 0; s < 4; ++s) {
        float s1i = s1L[h * NN + i0 + 16 * s + iL];
        float vv  = s1i + m4;
        float cii = fmaxf(vv, ALPHA_LR * vv);     // lrelu row shift (log2 domain)
        _Float16 a = (_Float16)(s1i - cii);
        _Float16 b = (_Float16)(ALPHA_LR * s1i - cii);
        A2[s] = (f16x2){a, a};
        B2[s] = (f16x2){b, b};
    }
    const f16x2 al2 = (f16x2){(_Float16)ALPHA_LR, (_Float16)ALPHA_LR};

    f32x4 acc[4][MM][4];
    f32x4 accD[4][MM];
    #pragma unroll
    for (int s = 0; s < 4; ++s)
        #pragma unroll
        for (int m = 0; m < MM; ++m) {
            accD[s][m] = (f32x4){0.f, 0.f, 0.f, 0.f};
            #pragma unroll
            for (int t = 0; t < 4; ++t) acc[s][m][t] = (f32x4){0.f, 0.f, 0.f, 0.f};
        }

    f16x8 bones;
    #pragma unroll
    for (int e = 0; e < 8; ++e) bones[e] = (_Float16)1.0f;

    const _Float16* s2row = s2h + h * NN;
    const _Float16* brow = whT + (size_t)(h * 64 + iL) * NN;   // + 16t*NN + j
    const int qshift = quad * 8;
    const int jbase = wave * 512;

    const unsigned long long* pB[MM][4];
    #pragma unroll
    for (int m = 0; m < MM; ++m)
        #pragma unroll
        for (int s = 0; s < 4; ++s)
            pB[m][s] = bitsT + (size_t)m * 64 * NN + i0 + 16 * s + iL;

    #pragma unroll 1
    for (int it = 0; it < 8; ++it) {
        const int jc = jbase + it * 64;
        const int jw = jc >> 6;
        unsigned long long bm[MM][4];
        #pragma unroll
        for (int m = 0; m < MM; ++m)
            #pragma unroll
            for (int s = 0; s < 4; ++s)
                bm[m][s] = pB[m][s][(size_t)jw * NN];

        #pragma unroll
        for (int half = 0; half < 2; ++half) {
            const int jb = jc + 32 * half;
            // shared b-fragments (amortized over 4 subtiles)
            f16x8 bfr[4];
            #pragma unroll
            for (int t = 0; t < 4; ++t)
                bfr[t] = *(const f16x8*)(brow + (size_t)(16 * t) * NN + jb + qshift);

            const W8 s2v = *(const W8*)(s2row + jb + qshift);  // 8 f16 (4 pairs)
            const int shft = 32 * half + qshift;

            #pragma unroll
            for (int s = 0; s < 4; ++s) {
                uint32_t rs0 = (uint32_t)(bm[0][s] >> shft) & 0xFFu;
                uint32_t rs1 = (uint32_t)(bm[1][s] >> shft) & 0xFFu;
                uint32_t V0 = rs0 | (rs0 << 15);   // bit 2k+1 -> bit 2k+16
                uint32_t V1 = rs1 | (rs1 << 15);
                W8 a0, a1v;
                #pragma unroll
                for (int k = 0; k < 4; ++k) {
                    f16x2 z = s2v.p[k] + A2[s];               // v_pk_add_f16
                    f16x2 l = al2 * s2v.p[k] + B2[s];         // v_pk_fma_f16
                    f16x2 mx = pkmax(z, l);                   // v_pk_max_f16
                    f16x2 p = (f16x2){__ocml_exp2_f16(mx[0]), __ocml_exp2_f16(mx[1])};
                    a0.p[k]  = p * msk01(V0, k);              // v_pk_mul_f16
                    a1v.p[k] = p * msk01(V1, k);
                }
                #pragma unroll
                for (int t = 0; t < 4; ++t) {
                    acc[s][0][t] = mfma16(a0.v, bfr[t], acc[s][0][t]);
                    acc[s][1][t] = mfma16(a1v.v, bfr[t], acc[s][1][t]);
                }
                accD[s][0] = mfma16(a0.v, bones, accD[s][0]);
                accD[s][1] = mfma16(a1v.v, bones, accD[s][1]);
            }
        }
    }

    // ---- epilogue: per s, single 8-slot store + 4-wave finalize (2 syncs/s) ----
    // unrolled: acc[s] must be statically indexed or it gets a scratch home
    #pragma unroll
    for (int s = 0; s < 4; ++s) {
        __syncthreads();          // previous round's reads complete
        #pragma unroll
        for (int m = 0; m < MM; ++m) {
            #pragma unroll
            for (int t = 0; t < 4; ++t)
                *(f32x4*)&xr[wave][m][t][iL][quad * 4] = acc[s][m][t];
            if (iL == 0) *(f32x4*)&dr[wave][m][quad * 4] = accD[s][m];
        }
        __syncthreads();
        if (wave < 4) {
            const int t = wave;
            f32x4 n0 = (f32x4){0.f, 0.f, 0.f, 0.f};
            f32x4 n1 = (f32x4){0.f, 0.f, 0.f, 0.f};
            f32x4 d0 = (f32x4){0.f, 0.f, 0.f, 0.f};
            f32x4 d1 = (f32x4){0.f, 0.f, 0.f, 0.f};
            #pragma unroll
            for (int sl = 0; sl < 8; ++sl) {
                n0 += *(const f32x4*)&xr[sl][0][t][iL][quad * 4];
                n1 += *(const f32x4*)&xr[sl][1][t][iL][quad * 4];
                d0 += *(const f32x4*)&dr[sl][0][quad * 4];
                d1 += *(const f32x4*)&dr[sl][1][quad * 4];
            }
            const int i0s = i0 + 16 * s;
            #pragma unroll
            for (int r = 0; r < 4; ++r) {
                float v0 = n0[r] * fast_rcp(d0[r]);
                float v1 = n1[r] * fast_rcp(d1[r]);
                float e0 = v0 > 0.f ? v0 : (fast_exp2(v0 * LOG2E) - 1.f);
                float e1 = v1 > 0.f ? v1 : (fast_exp2(v1 * LOG2E) - 1.f);
                out[(size_t)(i0s + quad * 4 + r) * (HH * DD) + h * 64 + 16 * t + iL] = e0 + e1;
            }
        }
    }
}

extern "C" void kernel_launch(void* const* d_in, const int* in_sizes, int n_in,
                              void* d_out, int out_size, void* d_ws, size_t ws_size,
                              hipStream_t stream) {
    const float* x   = (const float*)d_in[0];
    const int*   adj = (const int*)d_in[1];
    const float* W   = (const float*)d_in[2];
    const float* a1  = (const float*)d_in[3];
    const float* a2  = (const float*)d_in[4];
    // d_in[5..7] (Ws, bs, q_sem) mathematically dead: softmax over size-1 axis == 1
    float* out = (float*)d_out;

    char* ws = (char*)d_ws;
    _Float16* wt   = (_Float16*)(ws);                 // 256 KB
    _Float16* whT  = (_Float16*)(ws + 262144);        // 2 MB
    float*    s1L  = (float*)(ws + 2359296);          // 64 KB
    _Float16* s2h  = (_Float16*)(ws + 2424832);       // 32 KB
    uint32_t* m4a  = (uint32_t*)(ws + 2457600);       // 16 B
    unsigned long long* bitsT = (unsigned long long*)(ws + 2490368); // 4 MB

    hipLaunchKernelGGL(k_prep, dim3(2560), dim3(256), 0, stream,
                       adj, W, wt, bitsT, m4a);
    hipLaunchKernelGGL(k_wh, dim3(256), dim3(512), 0, stream,
                       x, wt, a1, a2, whT, s1L, s2h, m4a);
    hipLaunchKernelGGL(k_attn, dim3(256), dim3(512), 0, stream,
                       whT, s1L, s2h, m4a, bitsT, out);
}